// Round 8
// baseline (484.453 us; speedup 1.0000x reference)
//
#include <hip/hip_runtime.h>
#include <cstdint>
#include <cstddef>

typedef __attribute__((ext_vector_type(8))) short short8;      // bf16x8 MFMA fragment
typedef __attribute__((ext_vector_type(8))) _Float16 half8;    // f16x8 LDS tile
typedef __attribute__((ext_vector_type(4))) float f32x4;       // fp32x4
typedef __attribute__((ext_vector_type(16))) float f32x16;     // fp32x16 accumulator (32x32)

#define C_ 512
#define S_ 4096
#define B_ 4
#define EPS_ 1e-6f
#define SCALE_ 0.04419417382415922f   // 512^-0.5, folded into q

__device__ __forceinline__ ushort f2bf(float f) {
    union { float f; uint32_t u; } v; v.f = f;
    uint32_t r = v.u + 0x7FFFu + ((v.u >> 16) & 1u);
    return (ushort)(r >> 16);
}

// ---------------- weight fp32 -> bf16 ----------------
__global__ void wconv_kernel(const float* __restrict__ wq, const float* __restrict__ wk,
                             const float* __restrict__ wv, const float* __restrict__ wo,
                             ushort* __restrict__ out) {
    int i = blockIdx.x * 256 + threadIdx.x;   // grid covers exactly 262144
    out[i]          = f2bf(wq[i]);
    out[262144 + i] = f2bf(wk[i]);
    out[524288 + i] = f2bf(wv[i]);
    out[786432 + i] = f2bf(wo[i]);
}

// ---------------- GroupNorm stats: one block per (b,g) ----------------
__global__ __launch_bounds__(512) void gn_stats_kernel(const float* __restrict__ x,
                                                       float* __restrict__ stats) {
    int bg = blockIdx.x;                       // b*32+g ; channels contiguous
    const float* xp = x + (size_t)bg * 16 * S_;
    float sum = 0.f, ss = 0.f;
    for (int i = threadIdx.x; i < 16 * S_; i += 512) {
        float v = xp[i];
        sum += v; ss += v * v;
    }
    #pragma unroll
    for (int off = 32; off; off >>= 1) {
        sum += __shfl_down(sum, off);
        ss  += __shfl_down(ss, off);
    }
    __shared__ float r0[8], r1[8];
    int wid = threadIdx.x >> 6;
    if ((threadIdx.x & 63) == 0) { r0[wid] = sum; r1[wid] = ss; }
    __syncthreads();
    if (threadIdx.x == 0) {
        float ts = 0.f, tq = 0.f;
        #pragma unroll
        for (int w = 0; w < 8; w++) { ts += r0[w]; tq += r1[w]; }
        float mean = ts / 65536.f;
        float var  = tq / 65536.f - mean * mean;
        stats[bg * 2]     = mean;
        stats[bg * 2 + 1] = rsqrtf(var + EPS_);
    }
}

// ---------------- GroupNorm apply + transpose to h_t[s][c] bf16 ----------------
__global__ __launch_bounds__(256) void gn_apply_kernel(const float* __restrict__ x,
        const float* __restrict__ gamma, const float* __restrict__ beta,
        const float* __restrict__ stats, ushort* __restrict__ h_t) {
    int sc = blockIdx.x, g = blockIdx.y, b = blockIdx.z;
    int c0 = g * 16;
    int bg = b * 32 + g;
    float mean = stats[bg * 2], rstd = stats[bg * 2 + 1];
    int t = threadIdx.x;
    __shared__ float tile[16][257];
    const float* xp = x + ((size_t)b * C_ + c0) * S_ + sc * 256;
    {
        int c = t >> 4, s0 = (t & 15) * 4;
        const float* src = xp + (size_t)c * S_;
        #pragma unroll
        for (int j = 0; j < 4; j++) {
            float4 d = *(const float4*)(src + s0 + 64 * j);
            tile[c][s0 + 64 * j + 0] = d.x;
            tile[c][s0 + 64 * j + 1] = d.y;
            tile[c][s0 + 64 * j + 2] = d.z;
            tile[c][s0 + 64 * j + 3] = d.w;
        }
    }
    __syncthreads();
    {
        float vv[16];
        #pragma unroll
        for (int ci = 0; ci < 16; ci++) {
            float a = rstd * gamma[c0 + ci];
            float bb2 = beta[c0 + ci] - mean * a;
            vv[ci] = tile[ci][t] * a + bb2;
        }
        uint4 lo, hi;
        lo.x = (uint32_t)f2bf(vv[0])  | ((uint32_t)f2bf(vv[1])  << 16);
        lo.y = (uint32_t)f2bf(vv[2])  | ((uint32_t)f2bf(vv[3])  << 16);
        lo.z = (uint32_t)f2bf(vv[4])  | ((uint32_t)f2bf(vv[5])  << 16);
        lo.w = (uint32_t)f2bf(vv[6])  | ((uint32_t)f2bf(vv[7])  << 16);
        hi.x = (uint32_t)f2bf(vv[8])  | ((uint32_t)f2bf(vv[9])  << 16);
        hi.y = (uint32_t)f2bf(vv[10]) | ((uint32_t)f2bf(vv[11]) << 16);
        hi.z = (uint32_t)f2bf(vv[12]) | ((uint32_t)f2bf(vv[13]) << 16);
        hi.w = (uint32_t)f2bf(vv[14]) | ((uint32_t)f2bf(vv[15]) << 16);
        ushort* dst = h_t + ((size_t)b * S_ + sc * 256 + t) * C_ + c0;
        *(uint4*)dst = lo;
        *(uint4*)(dst + 8) = hi;
    }
}

// ---------------- GEMM: 128x128 tile, 32x32x16 MFMA, gload_lds dbuf ----
// out[o][s] = sum_c W[o][c] * Bt[s][c] (+bias)
// MODE 0: bf16 out transposed [B][S][C], val=(acc+bias)*scale, LDS-transposed store
// MODE 1: bf16 out natural    [B][C][S], val=acc+bias           (v)
// MODE 2: f32  out natural    [B][C][S], val=x+acc+bias         (final)
template <int MODE>
__global__ __launch_bounds__(256, 2) void gemm_kernel(
        const ushort* __restrict__ A,     // [512][512] bf16 weights (K contig)
        const ushort* __restrict__ Bt,    // [B][4096][512] bf16 (K contig)
        const float* __restrict__ bias,
        void* __restrict__ outp,
        const float* __restrict__ xres,
        float scale) {
    int bb = blockIdx.z;
    int m0 = blockIdx.y * 128;
    int n0 = blockIdx.x * 128;
    const ushort* Ap = A + (size_t)m0 * 512;
    const ushort* Bp = Bt + (size_t)bb * S_ * C_ + (size_t)n0 * 512;

    extern __shared__ char lds[];

    int t = threadIdx.x, lane = t & 63, wid = t >> 6;
    int l31 = lane & 31, lh = lane >> 5;
    int wm = (wid >> 1) * 64, wn = (wid & 1) * 64;

    f32x16 acc[2][2] = {};

    #define G_STAGE(sbuf, k0)                                                            \
        {                                                                                \
            char* Adst = lds + (sbuf) * 16384;                                           \
            char* Bdst = lds + 32768 + (sbuf) * 16384;                                   \
            _Pragma("unroll")                                                            \
            for (int i_ = 0; i_ < 4; i_++) {                                             \
                int cb = wid * 64 + i_ * 256;                                            \
                int cid = cb + lane;                                                     \
                int row = cid >> 3, c16 = cid & 7;                                       \
                int sw = ((c16 * 16) ^ ((row & 7) << 4));                                \
                const char* sa = (const char*)(Ap + (size_t)row * 512 + (k0)) + sw;      \
                __builtin_amdgcn_global_load_lds(                                        \
                    (const __attribute__((address_space(1))) unsigned int*)sa,           \
                    (__attribute__((address_space(3))) unsigned int*)(Adst + cb * 16),   \
                    16, 0, 0);                                                           \
                const char* sb = (const char*)(Bp + (size_t)row * 512 + (k0)) + sw;      \
                __builtin_amdgcn_global_load_lds(                                        \
                    (const __attribute__((address_space(1))) unsigned int*)sb,           \
                    (__attribute__((address_space(3))) unsigned int*)(Bdst + cb * 16),   \
                    16, 0, 0);                                                           \
            }                                                                            \
        }

    G_STAGE(0, 0);
    asm volatile("s_waitcnt vmcnt(0)" ::: "memory");
    __builtin_amdgcn_s_barrier();
    asm volatile("" ::: "memory");

    for (int k0 = 0; k0 < 512; k0 += 64) {
        int s = (k0 >> 6) & 1;
        if (k0 + 64 < 512) G_STAGE(s ^ 1, k0 + 64);
        char* Al = lds + s * 16384;
        char* Bl = lds + 32768 + s * 16384;
        #pragma unroll
        for (int ks = 0; ks < 4; ks++) {
            short8 af[2], bfr[2];
            #pragma unroll
            for (int i = 0; i < 2; i++) {
                int rowa = wm + i * 32 + l31;
                af[i] = *(const short8*)(Al + rowa * 128 + ((ks * 32 + lh * 16) ^ ((rowa & 7) << 4)));
                int rowb = wn + i * 32 + l31;
                bfr[i] = *(const short8*)(Bl + rowb * 128 + ((ks * 32 + lh * 16) ^ ((rowb & 7) << 4)));
            }
            #pragma unroll
            for (int i = 0; i < 2; i++)
                #pragma unroll
                for (int j = 0; j < 2; j++)
                    acc[i][j] = __builtin_amdgcn_mfma_f32_32x32x16_bf16(af[i], bfr[j], acc[i][j], 0, 0, 0);
        }
        asm volatile("s_waitcnt vmcnt(0) lgkmcnt(0)" ::: "memory");
        __builtin_amdgcn_s_barrier();
        asm volatile("" ::: "memory");
    }
    #undef G_STAGE

    if (MODE == 0) {
        // transpose through LDS: T[n][m] bf16, stride 272B, XOR swizzle ((n&7)<<4)
        char* T = lds;   // 128*272 = 34816 B
        #pragma unroll
        for (int i = 0; i < 2; i++) {
            #pragma unroll
            for (int q = 0; q < 4; q++) {
                int m_l = wm + i * 32 + q * 8 + 4 * lh;
                float bs[4];
                #pragma unroll
                for (int r = 0; r < 4; r++) bs[r] = bias[m0 + m_l + r];
                #pragma unroll
                for (int j = 0; j < 2; j++) {
                    int n_l = wn + j * 32 + l31;
                    uint2 pp;
                    pp.x = (uint32_t)f2bf((acc[i][j][q * 4 + 0] + bs[0]) * scale) |
                           ((uint32_t)f2bf((acc[i][j][q * 4 + 1] + bs[1]) * scale) << 16);
                    pp.y = (uint32_t)f2bf((acc[i][j][q * 4 + 2] + bs[2]) * scale) |
                           ((uint32_t)f2bf((acc[i][j][q * 4 + 3] + bs[3]) * scale) << 16);
                    *(uint2*)(T + n_l * 272 + ((m_l * 2) ^ ((n_l & 7) << 4))) = pp;
                }
            }
        }
        asm volatile("s_waitcnt lgkmcnt(0)" ::: "memory");
        __builtin_amdgcn_s_barrier();
        asm volatile("" ::: "memory");
        {
            int n_l = t >> 1, mh = (t & 1) * 64;
            const char* src = T + n_l * 272;
            int sw = (n_l & 7) << 4;
            ushort* dst = (ushort*)outp + ((size_t)bb * S_ + n0 + n_l) * C_ + m0 + mh;
            #pragma unroll
            for (int k = 0; k < 8; k++) {
                uint4 d = *(const uint4*)(src + ((mh * 2 + k * 16) ^ sw));
                *(uint4*)(dst + k * 8) = d;
            }
        }
        return;
    }

    // MODE 1/2 epilogue (n-contiguous stores)
    #pragma unroll
    for (int i = 0; i < 2; i++) {
        #pragma unroll
        for (int q = 0; q < 4; q++) {
            int mbase = m0 + wm + i * 32 + q * 8 + 4 * lh;
            float bs[4];
            #pragma unroll
            for (int r = 0; r < 4; r++) bs[r] = bias[mbase + r];
            #pragma unroll
            for (int j = 0; j < 2; j++) {
                int n = n0 + wn + j * 32 + l31;
                if (MODE == 1) {
                    ushort* O = (ushort*)outp + (size_t)bb * C_ * S_ + (size_t)mbase * S_ + n;
                    #pragma unroll
                    for (int r = 0; r < 4; r++) O[(size_t)r * S_] = f2bf(acc[i][j][q * 4 + r] + bs[r]);
                } else {
                    float* O = (float*)outp + (size_t)bb * C_ * S_ + (size_t)mbase * S_ + n;
                    const float* X = xres + (size_t)bb * C_ * S_ + (size_t)mbase * S_ + n;
                    #pragma unroll
                    for (int r = 0; r < 4; r++)
                        O[(size_t)r * S_] = X[(size_t)r * S_] + acc[i][j][q * 4 + r] + bs[r];
                }
            }
        }
    }
}

// ---------------- Flash attention: 2-phase fused loop [softmax | PV+S(next)] ----
// 1-D grid 256 XCD-clustered. QBLK=64, KVBLK=64, D=C=512.
// q_t,k_t: [B][S][C] bf16 (q pre-scaled).  v: [B][C][S] bf16.  ao_t: [B][S][C] bf16.
// LDS map (159560 B):
//   Kb0/Kb1 : 2 x [64 kv][1024B] XOR-swizzled                      0..65536..131072
//   S_lds   : [2 ch][64 q][72] f16 (stride 144B)                131072..149504
//   P_lds   : [64 q][144B] bf16                                 149504..158720
//   st_m/l/f: [64] f32 each; rflag[2]                           158720..159496
#define KBUF_SZ  65536
#define SLDS_OFF 131072
#define PLDS_OFF 149504
#define STM_OFF  158720

__device__ __forceinline__ void stage_k(const ushort* kp, int kv0, int wid, int lane, char* Kbuf) {
    #pragma unroll
    for (int p = 0; p < 8; p++) {
        int row = wid * 8 + p;
        const char* src = (const char*)(kp + (size_t)(kv0 + row) * C_) + ((lane * 16) ^ ((row & 7) << 4));
        __builtin_amdgcn_global_load_lds(
            (const __attribute__((address_space(1))) unsigned int*)src,
            (__attribute__((address_space(3))) unsigned int*)(Kbuf + row * 1024),
            16, 0, 0);
    }
}

__global__ __launch_bounds__(512, 2) void attn_kernel(const ushort* __restrict__ q_t,
        const ushort* __restrict__ k_t, const ushort* __restrict__ v,
        ushort* __restrict__ ao_t) {
    constexpr int NIT = S_ / 64;
    int id = blockIdx.x;
    int bb = (id & 7) >> 1;
    int qb = ((id & 1) << 5) | (id >> 3);
    int s0 = qb * 64;
    const ushort* qp = q_t + (size_t)bb * S_ * C_;
    const ushort* kp = k_t + (size_t)bb * S_ * C_;
    const ushort* vp = v   + (size_t)bb * C_ * S_;

    extern __shared__ char lds[];
    char* Kbuf0 = lds;
    char* Kbuf1 = lds + KBUF_SZ;
    _Float16* S_lds = (_Float16*)(lds + SLDS_OFF);
    char*  P_lds = lds + PLDS_OFF;
    float* st_m  = (float*)(lds + STM_OFF);
    float* st_l  = st_m + 64;
    float* st_f  = st_m + 128;
    int*   rflag = (int*)(st_m + 192);

    int t = threadIdx.x, lane = t & 63, wid = t >> 6;
    int l31 = lane & 31, lh = lane >> 5;
    int qt = (wid >> 2) & 1, nt = (wid >> 1) & 1, ch = wid & 1;

    if (t < 64) { st_m[t] = -1e30f; st_l[t] = 0.f; }
    if (t < 2) rflag[t] = 0;

    // Q fragments in registers: wave covers rows qt*32..+31, c-half ch (256 c)
    short8 qf[16];
    {
        const ushort* qrow = qp + (size_t)(s0 + qt * 32 + l31) * C_ + ch * 256 + lh * 8;
        #pragma unroll
        for (int ks = 0; ks < 16; ks++)
            qf[ks] = *(const short8*)(qrow + ks * 16);
    }
    f32x16 o_[2][2] = {};
    const ushort* vdb_base = vp + (size_t)(wid * 64 + l31) * S_ + lh * 8;

    // S-phase macro: compute S(tile) from Kbuf into S_lds
    #define S_PHASE(KB)                                                                   \
        {                                                                                 \
            f32x16 sacc = {};                                                             \
            int krow = nt * 32 + l31;                                                     \
            const char* kb = (KB) + krow * 1024;                                          \
            int sw = (krow & 7) << 4;                                                     \
            int cb0 = ch * 512 + lh * 16;                                                 \
            _Pragma("unroll")                                                             \
            for (int ks = 0; ks < 16; ks++) {                                             \
                short8 kf = *(const short8*)(kb + ((cb0 + ks * 32) ^ sw));                \
                sacc = __builtin_amdgcn_mfma_f32_32x32x16_bf16(qf[ks], kf, sacc, 0, 0, 0);\
            }                                                                             \
            _Float16* Sp = S_lds + (size_t)ch * 4608 + (size_t)(qt * 32) * 72 + nt * 32 + l31; \
            _Pragma("unroll")                                                             \
            for (int r = 0; r < 16; r++) {                                                \
                int qrow = (r & 3) + 8 * (r >> 2) + 4 * lh;                               \
                Sp[qrow * 72] = (_Float16)sacc[r];                                        \
            }                                                                             \
        }

    // prologue: stage K0,K1; compute S(0)
    stage_k(kp, 0, wid, lane, Kbuf0);
    stage_k(kp, 64, wid, lane, Kbuf1);
    asm volatile("s_waitcnt vmcnt(8)" ::: "memory");     // K0 complete (K1 in flight)
    __builtin_amdgcn_s_barrier();
    asm volatile("" ::: "memory");
    S_PHASE(Kbuf0);
    asm volatile("s_waitcnt lgkmcnt(0)" ::: "memory");
    __builtin_amdgcn_s_barrier();
    asm volatile("" ::: "memory");

    for (int it = 0; it < NIT; it++) {
        // ======== phase A: V prefetch + softmax(it) ========
        short8 vb[2][4];
        {
            const ushort* vdb = vdb_base + it * 64;
            #pragma unroll
            for (int dt = 0; dt < 2; dt++)
                #pragma unroll
                for (int ks2 = 0; ks2 < 4; ks2++)
                    vb[dt][ks2] = *(const short8*)(vdb + (size_t)dt * 32 * S_ + ks2 * 16);
        }
        if (t == 0 && it > 0) rflag[(it - 1) & 1] = 0;   // safe: readers were pre-barrier(it-1)
        {
            int row = t >> 3, j = t & 7;
            half8 h0 = *(const half8*)((const char*)S_lds + (size_t)row * 144 + j * 16);
            half8 h1 = *(const half8*)((const char*)S_lds + 9216 + (size_t)row * 144 + j * 16);
            float sv[8];
            #pragma unroll
            for (int i = 0; i < 8; i++) sv[i] = (float)h0[i] + (float)h1[i];
            float mx = sv[0];
            #pragma unroll
            for (int i = 1; i < 8; i++) mx = fmaxf(mx, sv[i]);
            mx = fmaxf(mx, __shfl_xor(mx, 1));
            mx = fmaxf(mx, __shfl_xor(mx, 2));
            mx = fmaxf(mx, __shfl_xor(mx, 4));
            float mold = st_m[row];
            bool need = (mx > mold + 6.0f);          // T13 defer-rescale
            float mnew = need ? mx : mold;
            if (need) rflag[it & 1] = 1;
            float ps = 0.f;
            uint32_t pk[4];
            #pragma unroll
            for (int i = 0; i < 4; i++) {
                float p0 = __expf(sv[2 * i]     - mnew);
                float p1 = __expf(sv[2 * i + 1] - mnew);
                ps += p0 + p1;
                pk[i] = (uint32_t)f2bf(p0) | ((uint32_t)f2bf(p1) << 16);
            }
            *(uint4*)(P_lds + (size_t)row * 144 + j * 16) = *(uint4*)pk;
            ps += __shfl_xor(ps, 1); ps += __shfl_xor(ps, 2); ps += __shfl_xor(ps, 4);
            if (j == 0) {
                float ef = need ? __expf(mold - mnew) : 1.0f;
                if (need) st_m[row] = mnew;
                st_f[row] = ef;
                st_l[row] = st_l[row] * ef + ps;
            }
        }
        asm volatile("s_waitcnt lgkmcnt(0)" ::: "memory");
        asm volatile("s_waitcnt vmcnt(8)" ::: "memory");  // K(it+1) staged; V(it) may fly
        __builtin_amdgcn_s_barrier();
        asm volatile("" ::: "memory");

        // ======== phase B: [rescale] + PV(it) + S(it+1) ========
        if (rflag[it & 1]) {
            #pragma unroll
            for (int qt2 = 0; qt2 < 2; qt2++) {
                f32x4 f0 = *(const f32x4*)(st_f + qt2 * 32 + 0  + 4 * lh);
                f32x4 f1 = *(const f32x4*)(st_f + qt2 * 32 + 8  + 4 * lh);
                f32x4 f2 = *(const f32x4*)(st_f + qt2 * 32 + 16 + 4 * lh);
                f32x4 f3 = *(const f32x4*)(st_f + qt2 * 32 + 24 + 4 * lh);
                float fr[16];
                #pragma unroll
                for (int e = 0; e < 4; e++) {
                    fr[e] = f0[e]; fr[4 + e] = f1[e]; fr[8 + e] = f2[e]; fr[12 + e] = f3[e];
                }
                #pragma unroll
                for (int dt = 0; dt < 2; dt++)
                    #pragma unroll
                    for (int r = 0; r < 16; r++)
                        o_[qt2][dt][r] *= fr[r];
            }
        }
        if (it + 2 < NIT)
            stage_k(kp, (it + 2) * 64, wid, lane, (it & 1) ? Kbuf1 : Kbuf0);
        {
            short8 pa[2][4];
            #pragma unroll
            for (int qt2 = 0; qt2 < 2; qt2++)
                #pragma unroll
                for (int ks2 = 0; ks2 < 4; ks2++)
                    pa[qt2][ks2] = *(const short8*)(P_lds + (size_t)(qt2 * 32 + l31) * 144 + ks2 * 32 + lh * 16);
            #pragma unroll
            for (int qt2 = 0; qt2 < 2; qt2++)
                #pragma unroll
                for (int dt = 0; dt < 2; dt++)
                    #pragma unroll
                    for (int ks2 = 0; ks2 < 4; ks2++)
                        o_[qt2][dt] = __builtin_amdgcn_mfma_f32_32x32x16_bf16(pa[qt2][ks2], vb[dt][ks2], o_[qt2][dt], 0, 0, 0);
        }
        if (it + 1 < NIT)
            S_PHASE((it & 1) ? Kbuf0 : Kbuf1);
        asm volatile("s_waitcnt lgkmcnt(0)" ::: "memory");
        __builtin_amdgcn_s_barrier();
        asm volatile("" ::: "memory");
    }
    #undef S_PHASE

    // ---- epilogue: O / l -> bf16 -> ao_t[s][c]
    #pragma unroll
    for (int qt2 = 0; qt2 < 2; qt2++) {
        f32x4 l0 = *(const f32x4*)(st_l + qt2 * 32 + 0  + 4 * lh);
        f32x4 l1 = *(const f32x4*)(st_l + qt2 * 32 + 8  + 4 * lh);
        f32x4 l2 = *(const f32x4*)(st_l + qt2 * 32 + 16 + 4 * lh);
        f32x4 l3 = *(const f32x4*)(st_l + qt2 * 32 + 24 + 4 * lh);
        float rl[16];
        #pragma unroll
        for (int e = 0; e < 4; e++) {
            rl[e] = 1.0f / l0[e]; rl[4 + e] = 1.0f / l1[e];
            rl[8 + e] = 1.0f / l2[e]; rl[12 + e] = 1.0f / l3[e];
        }
        #pragma unroll
        for (int dt = 0; dt < 2; dt++) {
            int d = wid * 64 + dt * 32 + l31;
            #pragma unroll
            for (int r = 0; r < 16; r++) {
                int q = qt2 * 32 + (r & 3) + 8 * (r >> 2) + 4 * lh;
                ao_t[((size_t)bb * S_ + s0 + q) * C_ + d] = f2bf(o_[qt2][dt][r] * rl[r]);
            }
        }
    }
}

extern "C" void kernel_launch(void* const* d_in, const int* in_sizes, int n_in,
                              void* d_out, int out_size, void* d_ws, size_t ws_size,
                              hipStream_t stream) {
    const float* x  = (const float*)d_in[0];
    const float* gg = (const float*)d_in[1];
    const float* gb = (const float*)d_in[2];
    const float* wq = (const float*)d_in[3];
    const float* bq = (const float*)d_in[4];
    const float* wk = (const float*)d_in[5];
    const float* bk = (const float*)d_in[6];
    const float* wv = (const float*)d_in[7];
    const float* bv = (const float*)d_in[8];
    const float* wo = (const float*)d_in[9];
    const float* bo = (const float*)d_in[10];
    float* out = (float*)d_out;

    char* ws = (char*)d_ws;
    const size_t BUF = (size_t)B_ * S_ * C_ * 2;    // 16 MB bf16 buffer
    ushort* h_t  = (ushort*)(ws);
    ushort* q_t  = (ushort*)(ws + BUF);
    ushort* k_t  = (ushort*)(ws + 2 * BUF);
    ushort* v_n  = (ushort*)(ws + 3 * BUF);
    ushort* ao_t = (ushort*)(ws + 4 * BUF);
    ushort* wb   = (ushort*)(ws + 5 * BUF);         // 4 x 262144 bf16
    float* stats = (float*)(ws + 5 * BUF + 4 * 524288);

    wconv_kernel<<<1024, 256, 0, stream>>>(wq, wk, wv, wo, wb);
    gn_stats_kernel<<<128, 512, 0, stream>>>(x, stats);
    gn_apply_kernel<<<dim3(16, 32, B_), 256, 0, stream>>>(x, gg, gb, stats, h_t);

    dim3 ggrid(32, 4, B_);
    gemm_kernel<0><<<ggrid, 256, 65536, stream>>>(wb,          h_t, bq, (void*)q_t, nullptr, SCALE_);
    gemm_kernel<0><<<ggrid, 256, 65536, stream>>>(wb + 262144, h_t, bk, (void*)k_t, nullptr, 1.0f);
    gemm_kernel<1><<<ggrid, 256, 65536, stream>>>(wb + 524288, h_t, bv, (void*)v_n, nullptr, 1.0f);

    attn_kernel<<<256, 512, 159560, stream>>>(q_t, k_t, v_n, ao_t);

    gemm_kernel<2><<<ggrid, 256, 65536, stream>>>(wb + 786432, ao_t, bo, (void*)out, x, 1.0f);
}